// Round 3
// baseline (575.524 us; speedup 1.0000x reference)
//
#include <hip/hip_runtime.h>
#include <hip/hip_bf16.h>
#include <stdint.h>

typedef __bf16 bf16;
typedef bf16 bf16x8 __attribute__((ext_vector_type(8)));
typedef bf16 bf16x4 __attribute__((ext_vector_type(4)));
typedef float f32x4 __attribute__((ext_vector_type(4)));

#define DEV static __device__ __forceinline__

constexpr int Bc = 16, Tc = 1029, Cc = 1024, Hc = 16, Dc = 64;
constexpr int KPAD = 1088;     // 17 * 64  (K/V padded length)
constexpr int QPAD = 1152;     // 9 * 128  (Q padded length)
constexpr int MPAD = 16512;    // 129 * 128
constexpr int NKT  = KPAD / 64;   // 17
constexpr int NVT  = KPAD / 32;   // 34

DEV void gload16(void* lds_dst, const void* gsrc) {
  __builtin_amdgcn_global_load_lds(
      (const __attribute__((address_space(1))) void*)gsrc,
      (__attribute__((address_space(3))) void*)lds_dst, 16, 0, 0);
}

// ---------------- cast x (f32 -> bf16), zero pad rows ----------------
__global__ __launch_bounds__(256) void cast_x(const float* __restrict__ x,
                                              bf16* __restrict__ xb) {
  const size_t i = ((size_t)blockIdx.x * 256 + threadIdx.x) * 8;
  const int row = (int)(i >> 10);
  bf16x8 o = {};
  if (row < Bc * Tc) {
    const float4* p = (const float4*)(x + i);
    float4 a = p[0], b = p[1];
    o[0] = (bf16)a.x; o[1] = (bf16)a.y; o[2] = (bf16)a.z; o[3] = (bf16)a.w;
    o[4] = (bf16)b.x; o[5] = (bf16)b.y; o[6] = (bf16)b.z; o[7] = (bf16)b.w;
  }
  *(bf16x8*)(xb + i) = o;
}

// ---------------- transpose + cast: W[rows][cols] f32 -> Wt[cols][rows] bf16
__global__ __launch_bounds__(256) void transpose_cast(const float* __restrict__ W,
                                                      bf16* __restrict__ Wt,
                                                      int rows, int cols) {
  __shared__ float tile[32][33];
  const int c0 = blockIdx.x * 32;
  const int r0 = blockIdx.y * 32;
  const int tr = threadIdx.x >> 5;   // 0..7
  const int tc = threadIdx.x & 31;   // 0..31
#pragma unroll
  for (int j = 0; j < 4; ++j)
    tile[tr + j * 8][tc] = W[(size_t)(r0 + tr + j * 8) * cols + c0 + tc];
  __syncthreads();
#pragma unroll
  for (int j = 0; j < 4; ++j)
    Wt[(size_t)(c0 + tr + j * 8) * rows + r0 + tc] = (bf16)tile[tc][tr + j * 8];
}

// ---------------- GEMM: C = A @ Bt^T + bias ----------------
template <bool OUT_BF16>
__global__ __launch_bounds__(256) void gemm_bt(const bf16* __restrict__ A,
                                               const bf16* __restrict__ Bt,
                                               const float* __restrict__ bias,
                                               void* __restrict__ Cout,
                                               int N, int K, int Mlim) {
  constexpr int BM = 128, BN = 128, BK = 32;
  __shared__ bf16 As[2][BM * BK];
  __shared__ bf16 Bs[2][BN * BK];
  const int tid  = threadIdx.x;
  const int lane = tid & 63;
  const int wave = tid >> 6;
  const int g = lane >> 4;
  const int c = lane & 15;
  const int m0 = blockIdx.y * BM;
  const int n0 = blockIdx.x * BN;
  const int wm = (wave >> 1) * 64;
  const int wn = (wave & 1) * 64;

  auto stage = [&](int buf, int k0) {
#pragma unroll
    for (int j = 0; j < 2; ++j) {
      int idx = j * 256 + tid;
      int row = idx >> 2, ch = idx & 3;
      gload16(&As[buf][idx * 8], A + (size_t)(m0 + row) * K + k0 + ch * 8);
    }
#pragma unroll
    for (int j = 0; j < 2; ++j) {
      int idx = j * 256 + tid;
      int row = idx >> 2, ch = idx & 3;
      gload16(&Bs[buf][idx * 8], Bt + (size_t)(n0 + row) * K + k0 + ch * 8);
    }
  };

  f32x4 acc[4][4] = {};
  stage(0, 0);
  __syncthreads();
  const int nk = K / BK;
  for (int kt = 0; kt < nk; ++kt) {
    const int buf = kt & 1;
    if (kt + 1 < nk) stage(buf ^ 1, (kt + 1) * BK);
    bf16x8 af[4], bfr[4];
#pragma unroll
    for (int i = 0; i < 4; ++i) {
      af[i]  = *(const bf16x8*)&As[buf][(wm + i * 16 + c) * BK + g * 8];
      bfr[i] = *(const bf16x8*)&Bs[buf][(wn + i * 16 + c) * BK + g * 8];
    }
#pragma unroll
    for (int i = 0; i < 4; ++i)
#pragma unroll
      for (int j = 0; j < 4; ++j)
        acc[i][j] = __builtin_amdgcn_mfma_f32_16x16x32_bf16(af[i], bfr[j], acc[i][j], 0, 0, 0);
    __syncthreads();
  }

#pragma unroll
  for (int i = 0; i < 4; ++i) {
    const int mb = m0 + wm + i * 16 + g * 4;
#pragma unroll
    for (int j = 0; j < 4; ++j) {
      const int n = n0 + wn + j * 16 + c;
      const float bv = bias[n];
#pragma unroll
      for (int r = 0; r < 4; ++r) {
        const int m = mb + r;
        if (m < Mlim) {
          float v = acc[i][j][r] + bv;
          if constexpr (OUT_BF16)
            ((bf16*)Cout)[(size_t)m * N + n] = (bf16)v;
          else
            ((float*)Cout)[(size_t)m * N + n] = v;
        }
      }
    }
  }
}

// ---------------- RoPE + reshape Q -> [bh][QPAD][64], K -> [bh][KPAD][64] ----
// Q gets 0.125 * log2(e) folded in (attention uses exp2).
__global__ __launch_bounds__(256) void rope_qk(const bf16* __restrict__ qkv,
                                               const float* __restrict__ cosT,
                                               const float* __restrict__ sinT,
                                               const int* __restrict__ npfx_p,
                                               bf16* __restrict__ Qh,
                                               bf16* __restrict__ Kh) {
  const int bt = blockIdx.x;
  const int b = bt / QPAD, t = bt % QPAD;
  const int h  = threadIdx.x >> 4;
  const int d0 = (threadIdx.x & 15) * 4;
  const size_t qoff = (((size_t)(b * Hc + h)) * QPAD + t) * Dc + d0;
  const size_t koff = (((size_t)(b * Hc + h)) * KPAD + t) * Dc + d0;
  if (t >= Tc) {
    bf16x4 z = {};
    *(bf16x4*)(Qh + qoff) = z;
    if (t < KPAD) *(bf16x4*)(Kh + koff) = z;
    return;
  }
  const int npfx = *npfx_p;
  const size_t inb = ((size_t)b * Tc + t) * 3072 + h * Dc;
  bf16x4 qv = *(const bf16x4*)(qkv + inb + d0);
  bf16x4 kv = *(const bf16x4*)(qkv + inb + 1024 + d0);
  float q[4], k[4];
#pragma unroll
  for (int u = 0; u < 4; ++u) { q[u] = (float)qv[u]; k[u] = (float)kv[u]; }
  if (t >= npfx) {
    const int p  = t - npfx;
    const int dp = (d0 < 32) ? d0 + 32 : d0 - 32;
    const float sgn = (d0 < 32) ? -1.f : 1.f;
    bf16x4 qp = *(const bf16x4*)(qkv + inb + dp);
    bf16x4 kp = *(const bf16x4*)(qkv + inb + 1024 + dp);
    float4 csv = *(const float4*)(cosT + (size_t)p * Dc + d0);
    float4 snv = *(const float4*)(sinT + (size_t)p * Dc + d0);
    float cs[4] = {csv.x, csv.y, csv.z, csv.w};
    float sn[4] = {snv.x, snv.y, snv.z, snv.w};
#pragma unroll
    for (int u = 0; u < 4; ++u) {
      q[u] = q[u] * cs[u] + sgn * (float)qp[u] * sn[u];
      k[u] = k[u] * cs[u] + sgn * (float)kp[u] * sn[u];
    }
  }
  bf16x4 qo, ko;
#pragma unroll
  for (int u = 0; u < 4; ++u) {
    qo[u] = (bf16)(q[u] * 0.18033688f);  // 1/8 * log2(e)
    ko[u] = (bf16)k[u];
  }
  *(bf16x4*)(Qh + qoff) = qo;
  *(bf16x4*)(Kh + koff) = ko;
}

// ---------------- V transpose -> Vt [bh][64][KPAD] ----------------
__global__ __launch_bounds__(256) void vtrans(const bf16* __restrict__ qkv,
                                              bf16* __restrict__ Vt) {
  __shared__ bf16 lds[64][40];
  const int blk = blockIdx.x;
  const int tt = blk % NVT;
  const int bh = blk / NVT;
  const int b = bh >> 4, h = bh & 15;
  const int t0 = tt * 32;
  const int tl = threadIdx.x >> 3;  // 0..31
  const int ch = threadIdx.x & 7;   // 0..7
  bf16x8 v = {};
  const int t = t0 + tl;
  if (t < Tc)
    v = *(const bf16x8*)(qkv + ((size_t)b * Tc + t) * 3072 + 2048 + h * Dc + ch * 8);
#pragma unroll
  for (int u = 0; u < 8; ++u) lds[ch * 8 + u][tl] = v[u];
  __syncthreads();
  const int d  = threadIdx.x >> 2;  // 0..63
  const int tc = threadIdx.x & 3;   // 0..3
  bf16x8 o = *(const bf16x8*)&lds[d][tc * 8];
  *(bf16x8*)(Vt + ((size_t)bh * Dc + d) * KPAD + t0 + tc * 8) = o;
}

// ---------------- flash attention v3: barrier-free, no K/V staging ----------
// 4 independent waves per block (32 q-rows each); K/V fragments read directly
// from global (L1/L2 serve reuse); per-wave P tile in swizzled LDS;
// row-sums via MFMA(P, ones); exp2-based online softmax with defer-max.
__global__ __launch_bounds__(256) void attn3(const bf16* __restrict__ Qh,
                                             const bf16* __restrict__ Kh,
                                             const bf16* __restrict__ Vt,
                                             bf16* __restrict__ y2d) {
  __shared__ bf16 Ps[4][32 * 64];   // per-wave P tile, XOR-swizzled rows (128B)
  const int bh = blockIdx.y;
  const int b = bh >> 4, h = bh & 15;
  const int tid = threadIdx.x;
  const int w = tid >> 6, lane = tid & 63;
  const int g = lane >> 4, c = lane & 15;
  const int q0 = blockIdx.x * 128 + w * 32;
  const bf16* Qb = Qh + (size_t)bh * QPAD * Dc;
  const bf16* Kb = Kh + (size_t)bh * KPAD * Dc;
  const bf16* Vb = Vt + (size_t)bh * Dc * KPAD;
  char* Pw = (char*)&Ps[w][0];

  // Q fragments
  bf16x8 qf[2][2];
#pragma unroll
  for (int fm = 0; fm < 2; ++fm)
#pragma unroll
    for (int kc = 0; kc < 2; ++kc)
      qf[fm][kc] = *(const bf16x8*)(Qb + (size_t)(q0 + fm * 16 + c) * Dc + kc * 32 + g * 8);

  bf16x8 ones;
#pragma unroll
  for (int u = 0; u < 8; ++u) ones[u] = (bf16)1.0f;

  float mrun[2][4], lrun[2][4];
  f32x4 oacc[2][4] = {};
#pragma unroll
  for (int fm = 0; fm < 2; ++fm)
#pragma unroll
    for (int r = 0; r < 4; ++r) { mrun[fm][r] = -1e30f; lrun[fm][r] = 0.f; }

  for (int kt = 0; kt < NKT; ++kt) {
    const int k0 = kt * 64;

    // --- K fragments direct from global ---
    bf16x8 kf[4][2];
#pragma unroll
    for (int fn = 0; fn < 4; ++fn)
#pragma unroll
      for (int kc = 0; kc < 2; ++kc)
        kf[fn][kc] = *(const bf16x8*)(Kb + (size_t)(k0 + fn * 16 + c) * Dc + kc * 32 + g * 8);

    // --- QK^T: S[32 q][64 k] (scores already in log2 units) ---
    f32x4 s[2][4] = {};
    __builtin_amdgcn_s_setprio(1);
#pragma unroll
    for (int fn = 0; fn < 4; ++fn)
#pragma unroll
      for (int kc = 0; kc < 2; ++kc)
#pragma unroll
        for (int fm = 0; fm < 2; ++fm)
          s[fm][fn] = __builtin_amdgcn_mfma_f32_16x16x32_bf16(qf[fm][kc], kf[fn][kc], s[fm][fn], 0, 0, 0);
    __builtin_amdgcn_s_setprio(0);

    // --- V fragments: issue loads now, consumed after softmax ---
    bf16x8 vf[4][2];
#pragma unroll
    for (int fd = 0; fd < 4; ++fd)
#pragma unroll
      for (int kc = 0; kc < 2; ++kc)
        vf[fd][kc] = *(const bf16x8*)(Vb + (size_t)(fd * 16 + c) * KPAD + k0 + kc * 32 + g * 8);

    // --- tail mask ---
    if (k0 + 64 > Tc) {
#pragma unroll
      for (int fn = 0; fn < 4; ++fn)
        if (k0 + fn * 16 + c >= Tc) {
#pragma unroll
          for (int fm = 0; fm < 2; ++fm)
#pragma unroll
            for (int r = 0; r < 4; ++r) s[fm][fn][r] = -1e30f;
        }
    }

    // --- online softmax (exp2 domain) with defer-max ---
#pragma unroll
    for (int fm = 0; fm < 2; ++fm) {
      f32x4 mx;
#pragma unroll
      for (int r = 0; r < 4; ++r)
        mx[r] = fmaxf(fmaxf(s[fm][0][r], s[fm][1][r]), fmaxf(s[fm][2][r], s[fm][3][r]));
#pragma unroll
      for (int msk = 1; msk < 16; msk <<= 1)
#pragma unroll
        for (int r = 0; r < 4; ++r) mx[r] = fmaxf(mx[r], __shfl_xor(mx[r], msk));
      const bool allok = (mx[0] - mrun[fm][0] <= 11.f) && (mx[1] - mrun[fm][1] <= 11.f) &&
                         (mx[2] - mrun[fm][2] <= 11.f) && (mx[3] - mrun[fm][3] <= 11.f);
      if (!__all(allok)) {
#pragma unroll
        for (int r = 0; r < 4; ++r) {
          const float mnew = fmaxf(mrun[fm][r], mx[r]);
          const float al = __builtin_amdgcn_exp2f(mrun[fm][r] - mnew);
          mrun[fm][r] = mnew;
          lrun[fm][r] *= al;
#pragma unroll
          for (int fd = 0; fd < 4; ++fd) oacc[fm][fd][r] *= al;
        }
      }
#pragma unroll
      for (int fn = 0; fn < 4; ++fn)
#pragma unroll
        for (int r = 0; r < 4; ++r) {
          const float p = __builtin_amdgcn_exp2f(s[fm][fn][r] - mrun[fm][r]);
          const int row = fm * 16 + g * 4 + r;
          *(bf16*)(Pw + row * 128 + (((fn * 16 + c) * 2) ^ ((row & 7) << 4))) = (bf16)p;
        }
    }

    // --- P fragments ---
    bf16x8 pf[2][2];
#pragma unroll
    for (int fm = 0; fm < 2; ++fm) {
      const int row = fm * 16 + c;
      const int sw = (row & 7) << 4;
#pragma unroll
      for (int kc = 0; kc < 2; ++kc)
        pf[fm][kc] = *(const bf16x8*)(Pw + row * 128 + ((kc * 64 + g * 16) ^ sw));
    }

    // --- PV + row-sum via MFMA(P, ones) ---
    f32x4 ps[2] = {};
    __builtin_amdgcn_s_setprio(1);
#pragma unroll
    for (int fm = 0; fm < 2; ++fm)
#pragma unroll
      for (int kc = 0; kc < 2; ++kc)
        ps[fm] = __builtin_amdgcn_mfma_f32_16x16x32_bf16(pf[fm][kc], ones, ps[fm], 0, 0, 0);
#pragma unroll
    for (int fd = 0; fd < 4; ++fd)
#pragma unroll
      for (int kc = 0; kc < 2; ++kc)
#pragma unroll
        for (int fm = 0; fm < 2; ++fm)
          oacc[fm][fd] = __builtin_amdgcn_mfma_f32_16x16x32_bf16(pf[fm][kc], vf[fd][kc], oacc[fm][fd], 0, 0, 0);
    __builtin_amdgcn_s_setprio(0);
#pragma unroll
    for (int fm = 0; fm < 2; ++fm)
#pragma unroll
      for (int r = 0; r < 4; ++r) lrun[fm][r] += ps[fm][r];
  }

#pragma unroll
  for (int fm = 0; fm < 2; ++fm)
#pragma unroll
    for (int r = 0; r < 4; ++r) {
      const int trow = q0 + fm * 16 + g * 4 + r;
      if (trow < Tc) {
        const float inv = 1.f / lrun[fm][r];
#pragma unroll
        for (int fd = 0; fd < 4; ++fd)
          y2d[((size_t)b * Tc + trow) * Cc + h * Dc + fd * 16 + c] =
              (bf16)(oacc[fm][fd][r] * inv);
      }
    }
}

// ---------------- launch ----------------
extern "C" void kernel_launch(void* const* d_in, const int* in_sizes, int n_in,
                              void* d_out, int out_size, void* d_ws, size_t ws_size,
                              hipStream_t stream) {
  const float* x    = (const float*)d_in[0];
  const float* Wqkv = (const float*)d_in[1];
  const float* bqkv = (const float*)d_in[2];
  const float* Wout = (const float*)d_in[3];
  const float* bout = (const float*)d_in[4];
  const float* cosT = (const float*)d_in[5];
  const float* sinT = (const float*)d_in[6];
  const int*   npfx = (const int*)d_in[7];

  char* ws = (char*)d_ws;
  size_t off = 0;
  auto alloc = [&](size_t bytes) {
    char* p = ws + off;
    off = (off + bytes + 255) & ~(size_t)255;
    return p;
  };
  bf16* xb  = (bf16*)alloc((size_t)MPAD * 1024 * 2);   // also reused as y2d
  bf16* Wt1 = (bf16*)alloc((size_t)3072 * 1024 * 2);
  bf16* Wt2 = (bf16*)alloc((size_t)1024 * 1024 * 2);
  bf16* qkv = (bf16*)alloc((size_t)MPAD * 3072 * 2);
  bf16* Qh  = (bf16*)alloc((size_t)256 * QPAD * 64 * 2);
  bf16* Kh  = (bf16*)alloc((size_t)256 * KPAD * 64 * 2);
  bf16* Vt  = (bf16*)alloc((size_t)256 * KPAD * 64 * 2);
  bf16* y2d = xb;
  if (off > ws_size) return;

  cast_x<<<dim3(MPAD * 1024 / 2048), dim3(256), 0, stream>>>(x, xb);
  transpose_cast<<<dim3(3072 / 32, 1024 / 32), dim3(256), 0, stream>>>(Wqkv, Wt1, 1024, 3072);
  transpose_cast<<<dim3(1024 / 32, 1024 / 32), dim3(256), 0, stream>>>(Wout, Wt2, 1024, 1024);
  gemm_bt<true><<<dim3(3072 / 128, MPAD / 128), dim3(256), 0, stream>>>(
      xb, Wt1, bqkv, (void*)qkv, 3072, 1024, MPAD);
  rope_qk<<<dim3(Bc * QPAD), dim3(256), 0, stream>>>(qkv, cosT, sinT, npfx, Qh, Kh);
  vtrans<<<dim3(256 * NVT), dim3(256), 0, stream>>>(qkv, Vt);
  attn3<<<dim3(QPAD / 128, 256), dim3(256), 0, stream>>>(Qh, Kh, Vt, y2d);
  gemm_bt<false><<<dim3(1024 / 128, MPAD / 128), dim3(256), 0, stream>>>(
      y2d, Wt2, bout, d_out, 1024, 1024, Bc * Tc);
}

// Round 4
// 394.995 us; speedup vs baseline: 1.4570x; 1.4570x over previous
//
#include <hip/hip_runtime.h>
#include <hip/hip_bf16.h>
#include <stdint.h>

typedef __bf16 bf16;
typedef bf16 bf16x8 __attribute__((ext_vector_type(8)));
typedef bf16 bf16x4 __attribute__((ext_vector_type(4)));
typedef float f32x4 __attribute__((ext_vector_type(4)));

#define DEV static __device__ __forceinline__

constexpr int Bc = 16, Tc = 1029, Cc = 1024, Hc = 16, Dc = 64;
constexpr int KPAD = 1088;     // 17 * 64  (K/V padded length)
constexpr int QPAD = 1152;     // 9 * 128  (Q padded length)
constexpr int MPAD = 16512;    // 129 * 128
constexpr int NKT  = KPAD / 64;   // 17
constexpr int NVT  = KPAD / 32;   // 34

DEV void gload16(void* lds_dst, const void* gsrc) {
  __builtin_amdgcn_global_load_lds(
      (const __attribute__((address_space(1))) void*)gsrc,
      (__attribute__((address_space(3))) void*)lds_dst, 16, 0, 0);
}

// ---------------- cast x (f32 -> bf16), zero pad rows ----------------
__global__ __launch_bounds__(256) void cast_x(const float* __restrict__ x,
                                              bf16* __restrict__ xb) {
  const size_t i = ((size_t)blockIdx.x * 256 + threadIdx.x) * 8;
  const int row = (int)(i >> 10);
  bf16x8 o = {};
  if (row < Bc * Tc) {
    const float4* p = (const float4*)(x + i);
    float4 a = p[0], b = p[1];
    o[0] = (bf16)a.x; o[1] = (bf16)a.y; o[2] = (bf16)a.z; o[3] = (bf16)a.w;
    o[4] = (bf16)b.x; o[5] = (bf16)b.y; o[6] = (bf16)b.z; o[7] = (bf16)b.w;
  }
  *(bf16x8*)(xb + i) = o;
}

// ---------------- transpose + cast: W[rows][cols] f32 -> Wt[cols][rows] bf16
__global__ __launch_bounds__(256) void transpose_cast(const float* __restrict__ W,
                                                      bf16* __restrict__ Wt,
                                                      int rows, int cols) {
  __shared__ float tile[32][33];
  const int c0 = blockIdx.x * 32;
  const int r0 = blockIdx.y * 32;
  const int tr = threadIdx.x >> 5;   // 0..7
  const int tc = threadIdx.x & 31;   // 0..31
#pragma unroll
  for (int j = 0; j < 4; ++j)
    tile[tr + j * 8][tc] = W[(size_t)(r0 + tr + j * 8) * cols + c0 + tc];
  __syncthreads();
#pragma unroll
  for (int j = 0; j < 4; ++j)
    Wt[(size_t)(c0 + tr + j * 8) * rows + r0 + tc] = (bf16)tile[tc][tr + j * 8];
}

// ---------------- GEMM: C = A @ Bt^T + bias ----------------
template <bool OUT_BF16>
__global__ __launch_bounds__(256) void gemm_bt(const bf16* __restrict__ A,
                                               const bf16* __restrict__ Bt,
                                               const float* __restrict__ bias,
                                               void* __restrict__ Cout,
                                               int N, int K, int Mlim) {
  constexpr int BM = 128, BN = 128, BK = 32;
  __shared__ bf16 As[2][BM * BK];
  __shared__ bf16 Bs[2][BN * BK];
  const int tid  = threadIdx.x;
  const int lane = tid & 63;
  const int wave = tid >> 6;
  const int g = lane >> 4;
  const int c = lane & 15;
  const int m0 = blockIdx.y * BM;
  const int n0 = blockIdx.x * BN;
  const int wm = (wave >> 1) * 64;
  const int wn = (wave & 1) * 64;

  auto stage = [&](int buf, int k0) {
#pragma unroll
    for (int j = 0; j < 2; ++j) {
      int idx = j * 256 + tid;
      int row = idx >> 2, ch = idx & 3;
      gload16(&As[buf][idx * 8], A + (size_t)(m0 + row) * K + k0 + ch * 8);
    }
#pragma unroll
    for (int j = 0; j < 2; ++j) {
      int idx = j * 256 + tid;
      int row = idx >> 2, ch = idx & 3;
      gload16(&Bs[buf][idx * 8], Bt + (size_t)(n0 + row) * K + k0 + ch * 8);
    }
  };

  f32x4 acc[4][4] = {};
  stage(0, 0);
  __syncthreads();
  const int nk = K / BK;
  for (int kt = 0; kt < nk; ++kt) {
    const int buf = kt & 1;
    if (kt + 1 < nk) stage(buf ^ 1, (kt + 1) * BK);
    bf16x8 af[4], bfr[4];
#pragma unroll
    for (int i = 0; i < 4; ++i) {
      af[i]  = *(const bf16x8*)&As[buf][(wm + i * 16 + c) * BK + g * 8];
      bfr[i] = *(const bf16x8*)&Bs[buf][(wn + i * 16 + c) * BK + g * 8];
    }
#pragma unroll
    for (int i = 0; i < 4; ++i)
#pragma unroll
      for (int j = 0; j < 4; ++j)
        acc[i][j] = __builtin_amdgcn_mfma_f32_16x16x32_bf16(af[i], bfr[j], acc[i][j], 0, 0, 0);
    __syncthreads();
  }

#pragma unroll
  for (int i = 0; i < 4; ++i) {
    const int mb = m0 + wm + i * 16 + g * 4;
#pragma unroll
    for (int j = 0; j < 4; ++j) {
      const int n = n0 + wn + j * 16 + c;
      const float bv = bias[n];
#pragma unroll
      for (int r = 0; r < 4; ++r) {
        const int m = mb + r;
        if (m < Mlim) {
          float v = acc[i][j][r] + bv;
          if constexpr (OUT_BF16)
            ((bf16*)Cout)[(size_t)m * N + n] = (bf16)v;
          else
            ((float*)Cout)[(size_t)m * N + n] = v;
        }
      }
    }
  }
}

// ---------------- RoPE + reshape Q -> [bh][QPAD][64], K -> [bh][KPAD][64] ----
// Q gets 0.125 * log2(e) folded in (attention uses exp2).
__global__ __launch_bounds__(256) void rope_qk(const bf16* __restrict__ qkv,
                                               const float* __restrict__ cosT,
                                               const float* __restrict__ sinT,
                                               const int* __restrict__ npfx_p,
                                               bf16* __restrict__ Qh,
                                               bf16* __restrict__ Kh) {
  const int bt = blockIdx.x;
  const int b = bt / QPAD, t = bt % QPAD;
  const int h  = threadIdx.x >> 4;
  const int d0 = (threadIdx.x & 15) * 4;
  const size_t qoff = (((size_t)(b * Hc + h)) * QPAD + t) * Dc + d0;
  const size_t koff = (((size_t)(b * Hc + h)) * KPAD + t) * Dc + d0;
  if (t >= Tc) {
    bf16x4 z = {};
    *(bf16x4*)(Qh + qoff) = z;
    if (t < KPAD) *(bf16x4*)(Kh + koff) = z;
    return;
  }
  const int npfx = *npfx_p;
  const size_t inb = ((size_t)b * Tc + t) * 3072 + h * Dc;
  bf16x4 qv = *(const bf16x4*)(qkv + inb + d0);
  bf16x4 kv = *(const bf16x4*)(qkv + inb + 1024 + d0);
  float q[4], k[4];
#pragma unroll
  for (int u = 0; u < 4; ++u) { q[u] = (float)qv[u]; k[u] = (float)kv[u]; }
  if (t >= npfx) {
    const int p  = t - npfx;
    const int dp = (d0 < 32) ? d0 + 32 : d0 - 32;
    const float sgn = (d0 < 32) ? -1.f : 1.f;
    bf16x4 qp = *(const bf16x4*)(qkv + inb + dp);
    bf16x4 kp = *(const bf16x4*)(qkv + inb + 1024 + dp);
    float4 csv = *(const float4*)(cosT + (size_t)p * Dc + d0);
    float4 snv = *(const float4*)(sinT + (size_t)p * Dc + d0);
    float cs[4] = {csv.x, csv.y, csv.z, csv.w};
    float sn[4] = {snv.x, snv.y, snv.z, snv.w};
#pragma unroll
    for (int u = 0; u < 4; ++u) {
      q[u] = q[u] * cs[u] + sgn * (float)qp[u] * sn[u];
      k[u] = k[u] * cs[u] + sgn * (float)kp[u] * sn[u];
    }
  }
  bf16x4 qo, ko;
#pragma unroll
  for (int u = 0; u < 4; ++u) {
    qo[u] = (bf16)(q[u] * 0.18033688f);  // 1/8 * log2(e)
    ko[u] = (bf16)k[u];
  }
  *(bf16x4*)(Qh + qoff) = qo;
  *(bf16x4*)(Kh + koff) = ko;
}

// ---------------- V transpose -> Vt [bh][64][KPAD] ----------------
__global__ __launch_bounds__(256) void vtrans(const bf16* __restrict__ qkv,
                                              bf16* __restrict__ Vt) {
  __shared__ bf16 lds[64][40];
  const int blk = blockIdx.x;
  const int tt = blk % NVT;
  const int bh = blk / NVT;
  const int b = bh >> 4, h = bh & 15;
  const int t0 = tt * 32;
  const int tl = threadIdx.x >> 3;  // 0..31
  const int ch = threadIdx.x & 7;   // 0..7
  bf16x8 v = {};
  const int t = t0 + tl;
  if (t < Tc)
    v = *(const bf16x8*)(qkv + ((size_t)b * Tc + t) * 3072 + 2048 + h * Dc + ch * 8);
#pragma unroll
  for (int u = 0; u < 8; ++u) lds[ch * 8 + u][tl] = v[u];
  __syncthreads();
  const int d  = threadIdx.x >> 2;  // 0..63
  const int tc = threadIdx.x & 3;   // 0..3
  bf16x8 o = *(const bf16x8*)&lds[d][tc * 8];
  *(bf16x8*)(Vt + ((size_t)bh * Dc + d) * KPAD + t0 + tc * 8) = o;
}

// ---------------- flash attention v4: staged K/V + swapped (lane-local) softmax
// S^T = mfma(K,Q): lane holds one q-row's keys locally -> max = local fmax + 2 shfl,
// row-sum via MFMA(ones,P), P packed b64 stores, O^T = mfma(V^T,P^T).
__global__ __launch_bounds__(256, 3) void attn4(const bf16* __restrict__ Qh,
                                                const bf16* __restrict__ Kh,
                                                const bf16* __restrict__ Vt,
                                                bf16* __restrict__ y2d) {
  __shared__ bf16 Ks[2][64 * 64];   // [kv token][d], XOR-swizzled rows (128B)
  __shared__ bf16 Vs[2][64 * 64];   // [d][kv], XOR-swizzled rows
  __shared__ bf16 Ps[4][32 * 64];   // per-wave P [q][k], swizzled
  const int bh = blockIdx.y;
  const int b = bh >> 4, h = bh & 15;
  const int tid = threadIdx.x;
  const int w = tid >> 6, lane = tid & 63;
  const int g = lane >> 4, c = lane & 15;
  const int q0 = blockIdx.x * 128 + w * 32;
  const bf16* Qb = Qh + (size_t)bh * QPAD * Dc;
  const bf16* Kb = Kh + (size_t)bh * KPAD * Dc;
  const bf16* Vb = Vt + (size_t)bh * Dc * KPAD;
  char* Pw = (char*)&Ps[w][0];

  auto stage = [&](int buf, int k0) {
#pragma unroll
    for (int j = 0; j < 2; ++j) {
      int idx = j * 256 + tid;            // 512 x 16B = 8KB
      int row = idx >> 3;
      int scb = ((idx & 7) << 4) ^ ((row & 7) << 4);
      gload16((char*)&Ks[buf][0] + idx * 16,
              (const char*)(Kb + (size_t)(k0 + row) * 64) + scb);
    }
#pragma unroll
    for (int j = 0; j < 2; ++j) {
      int idx = j * 256 + tid;
      int row = idx >> 3;
      int scb = ((idx & 7) << 4) ^ ((row & 7) << 4);
      gload16((char*)&Vs[buf][0] + idx * 16,
              (const char*)(Vb + (size_t)row * KPAD + k0) + scb);
    }
  };

  // Q fragments (B-operand: col = c)
  bf16x8 qf[2][2];
#pragma unroll
  for (int fm = 0; fm < 2; ++fm)
#pragma unroll
    for (int kc = 0; kc < 2; ++kc)
      qf[fm][kc] = *(const bf16x8*)(Qb + (size_t)(q0 + fm * 16 + c) * Dc + kc * 32 + g * 8);

  bf16x8 ones;
#pragma unroll
  for (int u = 0; u < 8; ++u) ones[u] = (bf16)1.0f;

  float mrun[2] = {-1e30f, -1e30f}, lrun[2] = {0.f, 0.f};
  f32x4 oacc[2][4] = {};   // [fm(q tile)][fd(d tile)]: q=fm*16+c, d=fd*16+g*4+r

  stage(0, 0);
  __syncthreads();

  for (int kt = 0; kt < NKT; ++kt) {
    const int buf = kt & 1;
    const int k0 = kt * 64;
    if (kt + 1 < NKT) stage(buf ^ 1, (kt + 1) * 64);

    // --- S^T[k][q] = mfma(K-frag, Q-frag): lane (g,c): q=fm*16+c, k=fn*16+g*4+r
    f32x4 st[4][2] = {};
    __builtin_amdgcn_s_setprio(1);
#pragma unroll
    for (int fn = 0; fn < 4; ++fn) {
      const int row = fn * 16 + c;
      const int sw = (row & 7) << 4;
#pragma unroll
      for (int kc = 0; kc < 2; ++kc) {
        bf16x8 kf = *(const bf16x8*)((const char*)&Ks[buf][0] + row * 128 +
                                     ((kc * 64 + g * 16) ^ sw));
#pragma unroll
        for (int fm = 0; fm < 2; ++fm)
          st[fn][fm] = __builtin_amdgcn_mfma_f32_16x16x32_bf16(kf, qf[fm][kc], st[fn][fm], 0, 0, 0);
      }
    }
    __builtin_amdgcn_s_setprio(0);

    // --- tail mask (k is lane-local: fn*16+g*4+r) ---
    if (k0 + 64 > Tc) {
#pragma unroll
      for (int fn = 0; fn < 4; ++fn)
#pragma unroll
        for (int r = 0; r < 4; ++r)
          if (k0 + fn * 16 + g * 4 + r >= Tc) {
            st[fn][0][r] = -1e30f;
            st[fn][1][r] = -1e30f;
          }
    }

    // --- softmax: local max over 16 vals + 2 shfl; exp2; packed P store ---
    float mx[2];
#pragma unroll
    for (int fm = 0; fm < 2; ++fm) {
      float m0 = fmaxf(fmaxf(st[0][fm][0], st[0][fm][1]), fmaxf(st[0][fm][2], st[0][fm][3]));
      float m1 = fmaxf(fmaxf(st[1][fm][0], st[1][fm][1]), fmaxf(st[1][fm][2], st[1][fm][3]));
      float m2 = fmaxf(fmaxf(st[2][fm][0], st[2][fm][1]), fmaxf(st[2][fm][2], st[2][fm][3]));
      float m3 = fmaxf(fmaxf(st[3][fm][0], st[3][fm][1]), fmaxf(st[3][fm][2], st[3][fm][3]));
      float m = fmaxf(fmaxf(m0, m1), fmaxf(m2, m3));
      m = fmaxf(m, __shfl_xor(m, 16));
      m = fmaxf(m, __shfl_xor(m, 32));
      mx[fm] = m;
    }
    const bool ok = (mx[0] - mrun[0] <= 11.f) && (mx[1] - mrun[1] <= 11.f);
    if (!__all(ok)) {
#pragma unroll
      for (int fm = 0; fm < 2; ++fm) {
        const float mnew = fmaxf(mrun[fm], mx[fm]);
        const float al = __builtin_amdgcn_exp2f(mrun[fm] - mnew);
        mrun[fm] = mnew;
        lrun[fm] *= al;
#pragma unroll
        for (int fd = 0; fd < 4; ++fd) oacc[fm][fd] *= al;
      }
    }
#pragma unroll
    for (int fm = 0; fm < 2; ++fm) {
      const int row = fm * 16 + c;
      const int sw = (row & 7) << 4;
#pragma unroll
      for (int fn = 0; fn < 4; ++fn) {
        bf16x4 pv;
#pragma unroll
        for (int r = 0; r < 4; ++r)
          pv[r] = (bf16)__builtin_amdgcn_exp2f(st[fn][fm][r] - mrun[fm]);
        *(bf16x4*)(Pw + row * 128 + ((fn * 32 + g * 8) ^ sw)) = pv;
      }
    }

    // --- P^T fragments (B-operand col=q=c) + row-sum + PV (O^T) ---
    bf16x8 pf[2][2];
    f32x4 ps2[2] = {};
#pragma unroll
    for (int fm = 0; fm < 2; ++fm) {
      const int row = fm * 16 + c;
      const int sw = (row & 7) << 4;
#pragma unroll
      for (int kc = 0; kc < 2; ++kc) {
        pf[fm][kc] = *(const bf16x8*)(Pw + row * 128 + ((kc * 64 + g * 16) ^ sw));
        ps2[fm] = __builtin_amdgcn_mfma_f32_16x16x32_bf16(ones, pf[fm][kc], ps2[fm], 0, 0, 0);
      }
    }
    __builtin_amdgcn_s_setprio(1);
#pragma unroll
    for (int fd = 0; fd < 4; ++fd) {
      const int row = fd * 16 + c;
      const int sw = (row & 7) << 4;
#pragma unroll
      for (int kc = 0; kc < 2; ++kc) {
        bf16x8 vf = *(const bf16x8*)((const char*)&Vs[buf][0] + row * 128 +
                                     ((kc * 64 + g * 16) ^ sw));
#pragma unroll
        for (int fm = 0; fm < 2; ++fm)
          oacc[fm][fd] = __builtin_amdgcn_mfma_f32_16x16x32_bf16(vf, pf[fm][kc], oacc[fm][fd], 0, 0, 0);
      }
    }
    __builtin_amdgcn_s_setprio(0);
#pragma unroll
    for (int fm = 0; fm < 2; ++fm) lrun[fm] += ps2[fm][0];
    __syncthreads();
  }

  // --- epilogue: lane (g,c) owns q=fm*16+c, d=fd*16+g*4+r -> 8B packed stores
#pragma unroll
  for (int fm = 0; fm < 2; ++fm) {
    const int trow = q0 + fm * 16 + c;
    if (trow < Tc) {
      const float inv = 1.f / lrun[fm];
#pragma unroll
      for (int fd = 0; fd < 4; ++fd) {
        bf16x4 ov;
#pragma unroll
        for (int r = 0; r < 4; ++r) ov[r] = (bf16)(oacc[fm][fd][r] * inv);
        *(bf16x4*)(y2d + ((size_t)b * Tc + trow) * Cc + h * Dc + fd * 16 + g * 4) = ov;
      }
    }
  }
}

// ---------------- launch ----------------
extern "C" void kernel_launch(void* const* d_in, const int* in_sizes, int n_in,
                              void* d_out, int out_size, void* d_ws, size_t ws_size,
                              hipStream_t stream) {
  const float* x    = (const float*)d_in[0];
  const float* Wqkv = (const float*)d_in[1];
  const float* bqkv = (const float*)d_in[2];
  const float* Wout = (const float*)d_in[3];
  const float* bout = (const float*)d_in[4];
  const float* cosT = (const float*)d_in[5];
  const float* sinT = (const float*)d_in[6];
  const int*   npfx = (const int*)d_in[7];

  char* ws = (char*)d_ws;
  size_t off = 0;
  auto alloc = [&](size_t bytes) {
    char* p = ws + off;
    off = (off + bytes + 255) & ~(size_t)255;
    return p;
  };
  bf16* xb  = (bf16*)alloc((size_t)MPAD * 1024 * 2);   // also reused as y2d
  bf16* Wt1 = (bf16*)alloc((size_t)3072 * 1024 * 2);
  bf16* Wt2 = (bf16*)alloc((size_t)1024 * 1024 * 2);
  bf16* qkv = (bf16*)alloc((size_t)MPAD * 3072 * 2);
  bf16* Qh  = (bf16*)alloc((size_t)256 * QPAD * 64 * 2);
  bf16* Kh  = (bf16*)alloc((size_t)256 * KPAD * 64 * 2);
  bf16* Vt  = (bf16*)alloc((size_t)256 * KPAD * 64 * 2);
  bf16* y2d = xb;
  if (off > ws_size) return;

  cast_x<<<dim3(MPAD * 1024 / 2048), dim3(256), 0, stream>>>(x, xb);
  transpose_cast<<<dim3(3072 / 32, 1024 / 32), dim3(256), 0, stream>>>(Wqkv, Wt1, 1024, 3072);
  transpose_cast<<<dim3(1024 / 32, 1024 / 32), dim3(256), 0, stream>>>(Wout, Wt2, 1024, 1024);
  gemm_bt<true><<<dim3(3072 / 128, MPAD / 128), dim3(256), 0, stream>>>(
      xb, Wt1, bqkv, (void*)qkv, 3072, 1024, MPAD);
  rope_qk<<<dim3(Bc * QPAD), dim3(256), 0, stream>>>(qkv, cosT, sinT, npfx, Qh, Kh);
  vtrans<<<dim3(256 * NVT), dim3(256), 0, stream>>>(qkv, Vt);
  attn4<<<dim3(QPAD / 128, 256), dim3(256), 0, stream>>>(Qh, Kh, Vt, y2d);
  gemm_bt<false><<<dim3(1024 / 128, MPAD / 128), dim3(256), 0, stream>>>(
      y2d, Wt2, bout, d_out, 1024, 1024, Bc * Tc);
}

// Round 5
// 391.723 us; speedup vs baseline: 1.4692x; 1.0084x over previous
//
#include <hip/hip_runtime.h>
#include <hip/hip_bf16.h>
#include <stdint.h>

typedef __bf16 bf16;
typedef bf16 bf16x8 __attribute__((ext_vector_type(8)));
typedef bf16 bf16x4 __attribute__((ext_vector_type(4)));
typedef float f32x4 __attribute__((ext_vector_type(4)));

#define DEV static __device__ __forceinline__

constexpr int Bc = 16, Tc = 1029, Cc = 1024, Hc = 16, Dc = 64;
constexpr int KPAD = 1088;     // 17 * 64  (K/V padded length)
constexpr int QPAD = 1152;     // 9 * 128  (Q padded length)
constexpr int MPAD = 16512;    // 129 * 128
constexpr int NKT  = KPAD / 64;   // 17
constexpr int NVT  = KPAD / 32;   // 34

DEV void gload16(void* lds_dst, const void* gsrc) {
  __builtin_amdgcn_global_load_lds(
      (const __attribute__((address_space(1))) void*)gsrc,
      (__attribute__((address_space(3))) void*)lds_dst, 16, 0, 0);
}

// ---------------- cast x (f32 -> bf16), zero pad rows ----------------
__global__ __launch_bounds__(256) void cast_x(const float* __restrict__ x,
                                              bf16* __restrict__ xb) {
  const size_t i = ((size_t)blockIdx.x * 256 + threadIdx.x) * 8;
  const int row = (int)(i >> 10);
  bf16x8 o = {};
  if (row < Bc * Tc) {
    const float4* p = (const float4*)(x + i);
    float4 a = p[0], b = p[1];
    o[0] = (bf16)a.x; o[1] = (bf16)a.y; o[2] = (bf16)a.z; o[3] = (bf16)a.w;
    o[4] = (bf16)b.x; o[5] = (bf16)b.y; o[6] = (bf16)b.z; o[7] = (bf16)b.w;
  }
  *(bf16x8*)(xb + i) = o;
}

// ---------------- transpose + cast: W[rows][cols] f32 -> Wt[cols][rows] bf16
__global__ __launch_bounds__(256) void transpose_cast(const float* __restrict__ W,
                                                      bf16* __restrict__ Wt,
                                                      int rows, int cols) {
  __shared__ float tile[32][33];
  const int c0 = blockIdx.x * 32;
  const int r0 = blockIdx.y * 32;
  const int tr = threadIdx.x >> 5;   // 0..7
  const int tc = threadIdx.x & 31;   // 0..31
#pragma unroll
  for (int j = 0; j < 4; ++j)
    tile[tr + j * 8][tc] = W[(size_t)(r0 + tr + j * 8) * cols + c0 + tc];
  __syncthreads();
#pragma unroll
  for (int j = 0; j < 4; ++j)
    Wt[(size_t)(c0 + tr + j * 8) * rows + r0 + tc] = (bf16)tile[tc][tr + j * 8];
}

// ---------------- GEMM: C = A @ Bt^T + bias ----------------
// LDS tiles XOR-swizzled: chunk index (16B units within a 64B row) XORed with
// (row>>1)&3, applied on the pre-swizzled global source (gload_lds dest must
// stay linear) and on the fragment read. Bank group = (row&1)*16+4*(g^sw):
// 8 distinct groups over 16 lanes -> 2-way (free) instead of 8-way.
template <bool OUT_BF16>
__global__ __launch_bounds__(256) void gemm_bt(const bf16* __restrict__ A,
                                               const bf16* __restrict__ Bt,
                                               const float* __restrict__ bias,
                                               void* __restrict__ Cout,
                                               int N, int K, int Mlim) {
  constexpr int BM = 128, BN = 128, BK = 32;
  __shared__ bf16 As[2][BM * BK];
  __shared__ bf16 Bs[2][BN * BK];
  const int tid  = threadIdx.x;
  const int lane = tid & 63;
  const int wave = tid >> 6;
  const int g = lane >> 4;
  const int c = lane & 15;
  const int m0 = blockIdx.y * BM;
  const int n0 = blockIdx.x * BN;
  const int wm = (wave >> 1) * 64;
  const int wn = (wave & 1) * 64;

  auto stage = [&](int buf, int k0) {
#pragma unroll
    for (int j = 0; j < 2; ++j) {
      int idx = j * 256 + tid;
      int row = idx >> 2, ch = idx & 3;
      int sc = ((ch ^ ((row >> 1) & 3)) << 4);   // pre-swizzled source byte col
      gload16((char*)&As[buf][0] + idx * 16,
              (const char*)(A + (size_t)(m0 + row) * K + k0) + sc);
    }
#pragma unroll
    for (int j = 0; j < 2; ++j) {
      int idx = j * 256 + tid;
      int row = idx >> 2, ch = idx & 3;
      int sc = ((ch ^ ((row >> 1) & 3)) << 4);
      gload16((char*)&Bs[buf][0] + idx * 16,
              (const char*)(Bt + (size_t)(n0 + row) * K + k0) + sc);
    }
  };

  f32x4 acc[4][4] = {};
  stage(0, 0);
  __syncthreads();
  const int nk = K / BK;
  for (int kt = 0; kt < nk; ++kt) {
    const int buf = kt & 1;
    if (kt + 1 < nk) stage(buf ^ 1, (kt + 1) * BK);
    bf16x8 af[4], bfr[4];
#pragma unroll
    for (int i = 0; i < 4; ++i) {
      const int ra = wm + i * 16 + c;
      const int rb = wn + i * 16 + c;
      af[i]  = *(const bf16x8*)((const char*)&As[buf][0] + ra * 64 +
                                (((g ^ ((ra >> 1) & 3)) << 4)));
      bfr[i] = *(const bf16x8*)((const char*)&Bs[buf][0] + rb * 64 +
                                (((g ^ ((rb >> 1) & 3)) << 4)));
    }
#pragma unroll
    for (int i = 0; i < 4; ++i)
#pragma unroll
      for (int j = 0; j < 4; ++j)
        acc[i][j] = __builtin_amdgcn_mfma_f32_16x16x32_bf16(af[i], bfr[j], acc[i][j], 0, 0, 0);
    __syncthreads();
  }

#pragma unroll
  for (int i = 0; i < 4; ++i) {
    const int mb = m0 + wm + i * 16 + g * 4;
#pragma unroll
    for (int j = 0; j < 4; ++j) {
      const int n = n0 + wn + j * 16 + c;
      const float bv = bias[n];
#pragma unroll
      for (int r = 0; r < 4; ++r) {
        const int m = mb + r;
        if (m < Mlim) {
          float v = acc[i][j][r] + bv;
          if constexpr (OUT_BF16)
            ((bf16*)Cout)[(size_t)m * N + n] = (bf16)v;
          else
            ((float*)Cout)[(size_t)m * N + n] = v;
        }
      }
    }
  }
}

// ---------------- RoPE + reshape Q -> [bh][QPAD][64], K -> [bh][KPAD][64] ----
// Q gets 0.125 * log2(e) folded in (attention uses exp2).
__global__ __launch_bounds__(256) void rope_qk(const bf16* __restrict__ qkv,
                                               const float* __restrict__ cosT,
                                               const float* __restrict__ sinT,
                                               const int* __restrict__ npfx_p,
                                               bf16* __restrict__ Qh,
                                               bf16* __restrict__ Kh) {
  const int bt = blockIdx.x;
  const int b = bt / QPAD, t = bt % QPAD;
  const int h  = threadIdx.x >> 4;
  const int d0 = (threadIdx.x & 15) * 4;
  const size_t qoff = (((size_t)(b * Hc + h)) * QPAD + t) * Dc + d0;
  const size_t koff = (((size_t)(b * Hc + h)) * KPAD + t) * Dc + d0;
  if (t >= Tc) {
    bf16x4 z = {};
    *(bf16x4*)(Qh + qoff) = z;
    if (t < KPAD) *(bf16x4*)(Kh + koff) = z;
    return;
  }
  const int npfx = *npfx_p;
  const size_t inb = ((size_t)b * Tc + t) * 3072 + h * Dc;
  bf16x4 qv = *(const bf16x4*)(qkv + inb + d0);
  bf16x4 kv = *(const bf16x4*)(qkv + inb + 1024 + d0);
  float q[4], k[4];
#pragma unroll
  for (int u = 0; u < 4; ++u) { q[u] = (float)qv[u]; k[u] = (float)kv[u]; }
  if (t >= npfx) {
    const int p  = t - npfx;
    const int dp = (d0 < 32) ? d0 + 32 : d0 - 32;
    const float sgn = (d0 < 32) ? -1.f : 1.f;
    bf16x4 qp = *(const bf16x4*)(qkv + inb + dp);
    bf16x4 kp = *(const bf16x4*)(qkv + inb + 1024 + dp);
    float4 csv = *(const float4*)(cosT + (size_t)p * Dc + d0);
    float4 snv = *(const float4*)(sinT + (size_t)p * Dc + d0);
    float cs[4] = {csv.x, csv.y, csv.z, csv.w};
    float sn[4] = {snv.x, snv.y, snv.z, snv.w};
#pragma unroll
    for (int u = 0; u < 4; ++u) {
      q[u] = q[u] * cs[u] + sgn * (float)qp[u] * sn[u];
      k[u] = k[u] * cs[u] + sgn * (float)kp[u] * sn[u];
    }
  }
  bf16x4 qo, ko;
#pragma unroll
  for (int u = 0; u < 4; ++u) {
    qo[u] = (bf16)(q[u] * 0.18033688f);  // 1/8 * log2(e)
    ko[u] = (bf16)k[u];
  }
  *(bf16x4*)(Qh + qoff) = qo;
  *(bf16x4*)(Kh + koff) = ko;
}

// ---------------- V transpose -> Vt [bh][64][KPAD] ----------------
__global__ __launch_bounds__(256) void vtrans(const bf16* __restrict__ qkv,
                                              bf16* __restrict__ Vt) {
  __shared__ bf16 lds[64][40];
  const int blk = blockIdx.x;
  const int tt = blk % NVT;
  const int bh = blk / NVT;
  const int b = bh >> 4, h = bh & 15;
  const int t0 = tt * 32;
  const int tl = threadIdx.x >> 3;  // 0..31
  const int ch = threadIdx.x & 7;   // 0..7
  bf16x8 v = {};
  const int t = t0 + tl;
  if (t < Tc)
    v = *(const bf16x8*)(qkv + ((size_t)b * Tc + t) * 3072 + 2048 + h * Dc + ch * 8);
#pragma unroll
  for (int u = 0; u < 8; ++u) lds[ch * 8 + u][tl] = v[u];
  __syncthreads();
  const int d  = threadIdx.x >> 2;  // 0..63
  const int tc = threadIdx.x & 3;   // 0..3
  bf16x8 o = *(const bf16x8*)&lds[d][tc * 8];
  *(bf16x8*)(Vt + ((size_t)bh * Dc + d) * KPAD + t0 + tc * 8) = o;
}

// ---------------- flash attention v4: staged K/V + swapped (lane-local) softmax
// S^T = mfma(K,Q): lane holds one q-row's keys locally -> max = local fmax + 2 shfl,
// row-sum via MFMA(ones,P), P packed b64 stores, O^T = mfma(V^T,P^T).
__global__ __launch_bounds__(256, 3) void attn4(const bf16* __restrict__ Qh,
                                                const bf16* __restrict__ Kh,
                                                const bf16* __restrict__ Vt,
                                                bf16* __restrict__ y2d) {
  __shared__ bf16 Ks[2][64 * 64];   // [kv token][d], XOR-swizzled rows (128B)
  __shared__ bf16 Vs[2][64 * 64];   // [d][kv], XOR-swizzled rows
  __shared__ bf16 Ps[4][32 * 64];   // per-wave P [q][k], swizzled
  const int bh = blockIdx.y;
  const int b = bh >> 4, h = bh & 15;
  const int tid = threadIdx.x;
  const int w = tid >> 6, lane = tid & 63;
  const int g = lane >> 4, c = lane & 15;
  const int q0 = blockIdx.x * 128 + w * 32;
  const bf16* Qb = Qh + (size_t)bh * QPAD * Dc;
  const bf16* Kb = Kh + (size_t)bh * KPAD * Dc;
  const bf16* Vb = Vt + (size_t)bh * Dc * KPAD;
  char* Pw = (char*)&Ps[w][0];

  auto stage = [&](int buf, int k0) {
#pragma unroll
    for (int j = 0; j < 2; ++j) {
      int idx = j * 256 + tid;            // 512 x 16B = 8KB
      int row = idx >> 3;
      int scb = ((idx & 7) << 4) ^ ((row & 7) << 4);
      gload16((char*)&Ks[buf][0] + idx * 16,
              (const char*)(Kb + (size_t)(k0 + row) * 64) + scb);
    }
#pragma unroll
    for (int j = 0; j < 2; ++j) {
      int idx = j * 256 + tid;
      int row = idx >> 3;
      int scb = ((idx & 7) << 4) ^ ((row & 7) << 4);
      gload16((char*)&Vs[buf][0] + idx * 16,
              (const char*)(Vb + (size_t)row * KPAD + k0) + scb);
    }
  };

  // Q fragments (B-operand: col = c)
  bf16x8 qf[2][2];
#pragma unroll
  for (int fm = 0; fm < 2; ++fm)
#pragma unroll
    for (int kc = 0; kc < 2; ++kc)
      qf[fm][kc] = *(const bf16x8*)(Qb + (size_t)(q0 + fm * 16 + c) * Dc + kc * 32 + g * 8);

  bf16x8 ones;
#pragma unroll
  for (int u = 0; u < 8; ++u) ones[u] = (bf16)1.0f;

  float mrun[2] = {-1e30f, -1e30f}, lrun[2] = {0.f, 0.f};
  f32x4 oacc[2][4] = {};   // [fm(q tile)][fd(d tile)]: q=fm*16+c, d=fd*16+g*4+r

  stage(0, 0);
  __syncthreads();

  for (int kt = 0; kt < NKT; ++kt) {
    const int buf = kt & 1;
    const int k0 = kt * 64;
    if (kt + 1 < NKT) stage(buf ^ 1, (kt + 1) * 64);

    // --- S^T[k][q] = mfma(K-frag, Q-frag): lane (g,c): q=fm*16+c, k=fn*16+g*4+r
    f32x4 st[4][2] = {};
    __builtin_amdgcn_s_setprio(1);
#pragma unroll
    for (int fn = 0; fn < 4; ++fn) {
      const int row = fn * 16 + c;
      const int sw = (row & 7) << 4;
#pragma unroll
      for (int kc = 0; kc < 2; ++kc) {
        bf16x8 kf = *(const bf16x8*)((const char*)&Ks[buf][0] + row * 128 +
                                     ((kc * 64 + g * 16) ^ sw));
#pragma unroll
        for (int fm = 0; fm < 2; ++fm)
          st[fn][fm] = __builtin_amdgcn_mfma_f32_16x16x32_bf16(kf, qf[fm][kc], st[fn][fm], 0, 0, 0);
      }
    }
    __builtin_amdgcn_s_setprio(0);

    // --- tail mask (k is lane-local: fn*16+g*4+r) ---
    if (k0 + 64 > Tc) {
#pragma unroll
      for (int fn = 0; fn < 4; ++fn)
#pragma unroll
        for (int r = 0; r < 4; ++r)
          if (k0 + fn * 16 + g * 4 + r >= Tc) {
            st[fn][0][r] = -1e30f;
            st[fn][1][r] = -1e30f;
          }
    }

    // --- softmax: local max over 16 vals + 2 shfl; exp2; packed P store ---
    float mx[2];
#pragma unroll
    for (int fm = 0; fm < 2; ++fm) {
      float m0 = fmaxf(fmaxf(st[0][fm][0], st[0][fm][1]), fmaxf(st[0][fm][2], st[0][fm][3]));
      float m1 = fmaxf(fmaxf(st[1][fm][0], st[1][fm][1]), fmaxf(st[1][fm][2], st[1][fm][3]));
      float m2 = fmaxf(fmaxf(st[2][fm][0], st[2][fm][1]), fmaxf(st[2][fm][2], st[2][fm][3]));
      float m3 = fmaxf(fmaxf(st[3][fm][0], st[3][fm][1]), fmaxf(st[3][fm][2], st[3][fm][3]));
      float m = fmaxf(fmaxf(m0, m1), fmaxf(m2, m3));
      m = fmaxf(m, __shfl_xor(m, 16));
      m = fmaxf(m, __shfl_xor(m, 32));
      mx[fm] = m;
    }
    const bool ok = (mx[0] - mrun[0] <= 11.f) && (mx[1] - mrun[1] <= 11.f);
    if (!__all(ok)) {
#pragma unroll
      for (int fm = 0; fm < 2; ++fm) {
        const float mnew = fmaxf(mrun[fm], mx[fm]);
        const float al = __builtin_amdgcn_exp2f(mrun[fm] - mnew);
        mrun[fm] = mnew;
        lrun[fm] *= al;
#pragma unroll
        for (int fd = 0; fd < 4; ++fd) oacc[fm][fd] *= al;
      }
    }
#pragma unroll
    for (int fm = 0; fm < 2; ++fm) {
      const int row = fm * 16 + c;
      const int sw = (row & 7) << 4;
#pragma unroll
      for (int fn = 0; fn < 4; ++fn) {
        bf16x4 pv;
#pragma unroll
        for (int r = 0; r < 4; ++r)
          pv[r] = (bf16)__builtin_amdgcn_exp2f(st[fn][fm][r] - mrun[fm]);
        *(bf16x4*)(Pw + row * 128 + ((fn * 32 + g * 8) ^ sw)) = pv;
      }
    }

    // --- P^T fragments (B-operand col=q=c) + row-sum + PV (O^T) ---
    bf16x8 pf[2][2];
    f32x4 ps2[2] = {};
#pragma unroll
    for (int fm = 0; fm < 2; ++fm) {
      const int row = fm * 16 + c;
      const int sw = (row & 7) << 4;
#pragma unroll
      for (int kc = 0; kc < 2; ++kc) {
        pf[fm][kc] = *(const bf16x8*)(Pw + row * 128 + ((kc * 64 + g * 16) ^ sw));
        ps2[fm] = __builtin_amdgcn_mfma_f32_16x16x32_bf16(ones, pf[fm][kc], ps2[fm], 0, 0, 0);
      }
    }
    __builtin_amdgcn_s_setprio(1);
#pragma unroll
    for (int fd = 0; fd < 4; ++fd) {
      const int row = fd * 16 + c;
      const int sw = (row & 7) << 4;
#pragma unroll
      for (int kc = 0; kc < 2; ++kc) {
        bf16x8 vf = *(const bf16x8*)((const char*)&Vs[buf][0] + row * 128 +
                                     ((kc * 64 + g * 16) ^ sw));
#pragma unroll
        for (int fm = 0; fm < 2; ++fm)
          oacc[fm][fd] = __builtin_amdgcn_mfma_f32_16x16x32_bf16(vf, pf[fm][kc], oacc[fm][fd], 0, 0, 0);
      }
    }
    __builtin_amdgcn_s_setprio(0);
#pragma unroll
    for (int fm = 0; fm < 2; ++fm) lrun[fm] += ps2[fm][0];
    __syncthreads();
  }

  // --- epilogue: lane (g,c) owns q=fm*16+c, d=fd*16+g*4+r -> 8B packed stores
#pragma unroll
  for (int fm = 0; fm < 2; ++fm) {
    const int trow = q0 + fm * 16 + c;
    if (trow < Tc) {
      const float inv = 1.f / lrun[fm];
#pragma unroll
      for (int fd = 0; fd < 4; ++fd) {
        bf16x4 ov;
#pragma unroll
        for (int r = 0; r < 4; ++r) ov[r] = (bf16)(oacc[fm][fd][r] * inv);
        *(bf16x4*)(y2d + ((size_t)b * Tc + trow) * Cc + h * Dc + fd * 16 + g * 4) = ov;
      }
    }
  }
}

// ---------------- launch ----------------
extern "C" void kernel_launch(void* const* d_in, const int* in_sizes, int n_in,
                              void* d_out, int out_size, void* d_ws, size_t ws_size,
                              hipStream_t stream) {
  const float* x    = (const float*)d_in[0];
  const float* Wqkv = (const float*)d_in[1];
  const float* bqkv = (const float*)d_in[2];
  const float* Wout = (const float*)d_in[3];
  const float* bout = (const float*)d_in[4];
  const float* cosT = (const float*)d_in[5];
  const float* sinT = (const float*)d_in[6];
  const int*   npfx = (const int*)d_in[7];

  char* ws = (char*)d_ws;
  size_t off = 0;
  auto alloc = [&](size_t bytes) {
    char* p = ws + off;
    off = (off + bytes + 255) & ~(size_t)255;
    return p;
  };
  bf16* xb  = (bf16*)alloc((size_t)MPAD * 1024 * 2);   // also reused as y2d
  bf16* Wt1 = (bf16*)alloc((size_t)3072 * 1024 * 2);
  bf16* Wt2 = (bf16*)alloc((size_t)1024 * 1024 * 2);
  bf16* qkv = (bf16*)alloc((size_t)MPAD * 3072 * 2);
  bf16* Qh  = (bf16*)alloc((size_t)256 * QPAD * 64 * 2);
  bf16* Kh  = (bf16*)alloc((size_t)256 * KPAD * 64 * 2);
  bf16* Vt  = (bf16*)alloc((size_t)256 * KPAD * 64 * 2);
  bf16* y2d = xb;
  if (off > ws_size) return;

  cast_x<<<dim3(MPAD * 1024 / 2048), dim3(256), 0, stream>>>(x, xb);
  transpose_cast<<<dim3(3072 / 32, 1024 / 32), dim3(256), 0, stream>>>(Wqkv, Wt1, 1024, 3072);
  transpose_cast<<<dim3(1024 / 32, 1024 / 32), dim3(256), 0, stream>>>(Wout, Wt2, 1024, 1024);
  gemm_bt<true><<<dim3(3072 / 128, MPAD / 128), dim3(256), 0, stream>>>(
      xb, Wt1, bqkv, (void*)qkv, 3072, 1024, MPAD);
  rope_qk<<<dim3(Bc * QPAD), dim3(256), 0, stream>>>(qkv, cosT, sinT, npfx, Qh, Kh);
  vtrans<<<dim3(256 * NVT), dim3(256), 0, stream>>>(qkv, Vt);
  attn4<<<dim3(QPAD / 128, 256), dim3(256), 0, stream>>>(Qh, Kh, Vt, y2d);
  gemm_bt<false><<<dim3(1024 / 128, MPAD / 128), dim3(256), 0, stream>>>(
      y2d, Wt2, bout, d_out, 1024, 1024, Bc * Tc);
}